// Round 2
// baseline (885.187 us; speedup 1.0000x reference)
//
#include <hip/hip_runtime.h>

// VQ nearest-codebook: N=262144 rows x D=64, K=1024 codes.
// Numerics contract (matches np f32 reference incl. rounding ties):
//   dist_k = fl32( fl32(zsq - 2*dot_k) + cbsq_k ),  argmin -> lowest index wins.
// - dot_k: SINGLE sequential fmaf chain d=0..63 (bit-matches OpenBLAS sgemm
//   microkernel K-accumulation order). Do NOT re-associate / multi-accumulate:
//   tie rows (~400 of them) flip on ~1e-9 dot noise.
// - zsq/cbsq: f64-accumulated then rounded; whole-ulp zsq shifts cannot flip
//   ties (rounding commutes with whole-ulp shifts), so order is free here.

#define VQ_D 64
#define VQ_MAXK 1024

__global__ __launch_bounds__(256) void vq_argmin_kernel(
    const float* __restrict__ z_e,
    const float* __restrict__ cb,
    float* __restrict__ out,   // [N*D] z_q, then [N] indices (as float)
    int N, int K)
{
    __shared__ float s_cbsq[VQ_MAXK];

    // cb_sq per code: f64 accumulate, round once to f32.
    for (int k = threadIdx.x; k < K; k += blockDim.x) {
        const float* c = cb + (size_t)k * VQ_D;
        double s = 0.0;
        #pragma unroll
        for (int d = 0; d < VQ_D; ++d) { double v = (double)c[d]; s += v * v; }
        s_cbsq[k] = (float)s;
    }
    __syncthreads();

    const int n = blockIdx.x * blockDim.x + threadIdx.x;
    if (n >= N) return;

    // z row into registers (16 x float4).
    float z[VQ_D];
    const float4* zp = (const float4*)(z_e + (size_t)n * VQ_D);
    #pragma unroll
    for (int i = 0; i < VQ_D / 4; ++i) {
        float4 v = zp[i];
        z[4*i+0] = v.x; z[4*i+1] = v.y; z[4*i+2] = v.z; z[4*i+3] = v.w;
    }

    // ||z||^2: f64 accumulate, round once (tie-invariant to whole-ulp shifts).
    double zsqd = 0.0;
    #pragma unroll
    for (int d = 0; d < VQ_D; ++d) zsqd += (double)z[d] * (double)z[d];
    const float zsq = (float)zsqd;

    float best = 3.4e38f;
    int bestk = 0;

    for (int k = 0; k < K; ++k) {
        const float* __restrict__ c = cb + (size_t)k * VQ_D;  // wave-uniform -> s_load
        // Sequential fused-FMA chain, ascending d. DO NOT reorder.
        float s = 0.f;
        #pragma unroll
        for (int d = 0; d < VQ_D; ++d) s = fmaf(z[d], c[d], s);
        const float u    = zsq - 2.0f * s;     // fp32 round, as reference
        const float dist = u + s_cbsq[k];      // fp32 round, as reference
        if (dist < best) { best = dist; bestk = k; }  // strict <: lowest index wins ties
    }

    // z_q gather (codebook is L2/L3-resident).
    const float4* cq = (const float4*)(cb + (size_t)bestk * VQ_D);
    float4* oq = (float4*)(out + (size_t)n * VQ_D);
    #pragma unroll
    for (int i = 0; i < VQ_D / 4; ++i) oq[i] = cq[i];

    // Index as float (exact for k < 2^24).
    out[(size_t)N * VQ_D + n] = (float)bestk;
}

extern "C" void kernel_launch(void* const* d_in, const int* in_sizes, int n_in,
                              void* d_out, int out_size, void* d_ws, size_t ws_size,
                              hipStream_t stream) {
    const float* z_e = (const float*)d_in[0];
    const float* cb  = (const float*)d_in[1];
    float* out = (float*)d_out;

    const int N = in_sizes[0] / VQ_D;
    const int K = in_sizes[1] / VQ_D;

    const int block = 256;
    const int grid = (N + block - 1) / block;
    vq_argmin_kernel<<<grid, block, 0, stream>>>(z_e, cb, out, N, K);
}